// Round 2
// baseline (15457.700 us; speedup 1.0000x reference)
//
#include <hip/hip_runtime.h>

// Problem constants
#define B_   32
#define T_   256
#define N_   128
#define DIN_ 16
#define U_   64

// LDS layout (ushort elements)
#define PD 392   // node-major diffusion buffer pitch (>=384, +8 stagger)
#define PT 136   // ch-major (transposed) buffer pitch (>=128, +8 stagger)
#define LDS_US  (N_*PD + N_*PT)
#define LDS_BYTES (LDS_US*2)     // 135168 B

// Workspace (ushort elems): WT[co][k], k = dm*Cin + c (matrix-major), then S2 bf16
#define WT0G_OFF 0
#define WT0C_OFF (128*256)
#define WT1G_OFF (WT0C_OFF + 64*256)
#define WT1C_OFF (WT1G_OFF + 128*384)
#define WT_TOTAL (WT1C_OFF + 64*384)   // 122880 ushorts
#define S2_OFF   WT_TOTAL              // bf16 S2[128][128]

typedef __attribute__((ext_vector_type(8))) short bfrag;          // 8 bf16 (4 VGPR)
typedef __attribute__((ext_vector_type(4))) float ffrag;          // MFMA C/D
typedef __attribute__((ext_vector_type(4))) unsigned short us4;

__device__ __forceinline__ unsigned short f2b(float x) {          // fp32 -> bf16 RNE
  union { float f; unsigned u; } v; v.f = x;
  return (unsigned short)((v.u + 0x7fffu + ((v.u >> 16) & 1u)) >> 16);
}
__device__ __forceinline__ float sigm(float x) {
  float e = __expf(-x);
  return __builtin_amdgcn_rcpf(1.f + e);
}
__device__ __forceinline__ float tanh_(float x) {
  float e = __expf(2.f * x);   // tanh = 1 - 2/(1+e^{2x}); saturates cleanly
  return 1.f - 2.f * __builtin_amdgcn_rcpf(1.f + e);
}

// Chebyshev fold: dm0 -> W0 - W2, dm1 -> W1, dm2 -> 2*W2
// (x2 = 2*S2@xc - xc with S2 = S@S precomputed; -xc and 2* absorbed here)
__device__ __forceinline__ float wval(const float* w, int ncol, int cin, int K,
                                      int co, int k) {
  if (k >= K) return 0.f;                 // zero K-pad (L0: 240 -> 256)
  int dm = k / cin, c = k - dm * cin;
  if (dm == 0) return w[(c*3 + 0)*ncol + co] - w[(c*3 + 2)*ncol + co];
  if (dm == 1) return w[(c*3 + 1)*ncol + co];
  return 2.f * w[(c*3 + 2)*ncol + co];
}

__global__ void setup_wt(const float* __restrict__ w0g, const float* __restrict__ w0c,
                         const float* __restrict__ w1g, const float* __restrict__ w1c,
                         unsigned short* __restrict__ wt) {
  int i = blockIdx.x * blockDim.x + threadIdx.x;
  if (i >= WT_TOTAL) return;
  float v;
  if (i < WT0C_OFF) {
    int co = i >> 8, k = i & 255;
    v = wval(w0g, 128, 80, 240, co, k);
  } else if (i < WT1G_OFF) {
    int j = i - WT0C_OFF; int co = j >> 8, k = j & 255;
    v = wval(w0c, 64, 80, 240, co, k);
  } else if (i < WT1C_OFF) {
    int j = i - WT1G_OFF; int co = j / 384, k = j - co*384;
    v = wval(w1g, 128, 128, 384, co, k);
  } else {
    int j = i - WT1C_OFF; int co = j / 384, k = j - co*384;
    v = wval(w1c, 64, 128, 384, co, k);
  }
  wt[i] = f2b(v);
}

__global__ void setup_s2(const float* __restrict__ sup, unsigned short* __restrict__ s2) {
  int idx = blockIdx.x * blockDim.x + threadIdx.x;   // 16384
  int i = idx >> 7, j = idx & 127;
  float acc = 0.f;
#pragma unroll 4
  for (int k = 0; k < 128; ++k) acc += sup[i*128 + k] * sup[k*128 + j];
  s2[idx] = f2b(acc);
}

// Weight GEMM, node-split: wave owns its 16-node m-tile (arow = its A row base),
// computes all NT co-tiles. B streamed from global WT (L2-resident).
template<int KT, int NT>
__device__ __forceinline__ void wgemm(ffrag (&acc)[NT],
    const unsigned short* __restrict__ arow,
    const unsigned short* __restrict__ wtp, const int Kpad,
    const int ln, const int lq) {
  const ffrag fz = {0.f, 0.f, 0.f, 0.f};
#pragma unroll
  for (int n = 0; n < NT; ++n) acc[n] = fz;
#pragma unroll 4
  for (int ks = 0; ks < KT; ++ks) {
    bfrag a = *(const bfrag*)&arow[32*ks + 8*lq];
#pragma unroll
    for (int n = 0; n < NT; ++n) {
      bfrag bw = *(const bfrag*)&wtp[(16*n + ln)*Kpad + 32*ks + 8*lq];
      acc[n] = __builtin_amdgcn_mfma_f32_16x16x32_bf16(a, bw, acc[n], 0,0,0);
    }
  }
}

__global__ __launch_bounds__(512, 2) void dcgru(
    const float* __restrict__ xseq, const int* __restrict__ slen,
    const float* __restrict__ sup,
    const float* __restrict__ b0g, const float* __restrict__ b0c,
    const float* __restrict__ b1g, const float* __restrict__ b1c,
    const float* __restrict__ wfc, const float* __restrict__ bfc,
    const unsigned short* __restrict__ wt, float* __restrict__ out) {
  extern __shared__ unsigned short lds[];
  unsigned short* diffb = lds;             // [128][PD] node-major, k = dm*Cin+c
  unsigned short* difT  = lds + N_*PD;     // [128][PT] ch-major (diffuse B operand)
  const int b   = blockIdx.x;
  const int tid = threadIdx.x;
  const int w   = tid >> 6;                // wave 0..7: owns nodes [16w,16w+16)
  const int ln  = tid & 15;
  const int lq  = (tid >> 4) & 3;
  const int L   = slen[b];
  const unsigned short* __restrict__ arow = diffb + (16*w + ln)*PD;

  // ---- S and S2 A-frags for this wave's 16-row strip (8 bfrags = 32 VGPR) ----
  bfrag Sf[4], S2f[4];
#pragma unroll
  for (int ks = 0; ks < 4; ++ks) {
    const float* p = sup + (16*w + ln)*N_ + 32*ks + 8*lq;
    union { bfrag v; unsigned short u[8]; } tmp;
#pragma unroll
    for (int j = 0; j < 8; ++j) tmp.u[j] = f2b(p[j]);
    Sf[ks] = tmp.v;
    S2f[ks] = *(const bfrag*)&wt[S2_OFF + (16*w + ln)*N_ + 32*ks + 8*lq];
  }

  float bgv0[8], bcv0[4], bgv1[8], bcv1[4];
#pragma unroll
  for (int n = 0; n < 8; ++n) bgv0[n] = b0g[16*n + ln];
#pragma unroll
  for (int n = 0; n < 4; ++n) bcv0[n] = b0c[16*n + ln];
#pragma unroll
  for (int n = 0; n < 8; ++n) bgv1[n] = b1g[16*n + ln];
#pragma unroll
  for (int n = 0; n < 4; ++n) bcv1[n] = b1c[16*n + ln];

  // fp32 master hidden states: value[node = 16w + 4*lq + r][ch = 16*ct + ln]
  ffrag h0m[4], h1m[4];
  const ffrag fz = {0.f, 0.f, 0.f, 0.f};
#pragma unroll
  for (int c = 0; c < 4; ++c) { h0m[c] = fz; h1m[c] = fz; }

  // zero L0 K-pad cols [240,256) once (weights there are 0; avoid NaN garbage)
  for (int i = tid; i < N_*16; i += 512)
    diffb[(i >> 4)*PD + 240 + (i & 15)] = 0;

  // Diffusion: this wave computes its 16 output nodes for ch-tile nt.
  // dm1 = S@xc -> cols cin+ch; dm2 = S2@xc -> cols 2*cin+ch. One B-frag feeds both.
  auto diffuse = [&](int nt, int cin) {
    ffrag a1 = fz, a2 = fz;
    const int ch0 = 16*nt;
#pragma unroll
    for (int ks = 0; ks < 4; ++ks) {
      bfrag bf = *(const bfrag*)&difT[(ch0 + ln)*PT + 32*ks + 8*lq];
      a1 = __builtin_amdgcn_mfma_f32_16x16x32_bf16(Sf[ks],  bf, a1, 0,0,0);
      a2 = __builtin_amdgcn_mfma_f32_16x16x32_bf16(S2f[ks], bf, a2, 0,0,0);
    }
    const int node0 = 16*w + 4*lq;
    const int ch = ch0 + ln;
#pragma unroll
    for (int r = 0; r < 4; ++r) {
      diffb[(node0 + r)*PD + cin   + ch] = f2b(a1[r]);
      diffb[(node0 + r)*PD + 2*cin + ch] = f2b(a2[r]);
    }
  };

  // Dump an h-like reg tile (own node strip, 64 ch) into both LDS layouts.
  auto dumpH = [&](ffrag (&v)[4], int cb) {
    const int node0 = 16*w + 4*lq;
#pragma unroll
    for (int ct = 0; ct < 4; ++ct) {
      const int ch = cb + 16*ct + ln;
      unsigned short sv[4];
#pragma unroll
      for (int r = 0; r < 4; ++r) sv[r] = f2b(v[ct][r]);
#pragma unroll
      for (int r = 0; r < 4; ++r) diffb[(node0 + r)*PD + ch] = sv[r];
      us4 p4 = {sv[0], sv[1], sv[2], sv[3]};
      *(us4*)&difT[ch*PT + node0] = p4;
    }
  };

#pragma clang loop unroll(disable)
  for (int t = 0; t < L; ++t) {
    ffrag u0s[4], u1s[4];
    // ---------------- Layer 0 (Cin=80: x cols 0..15, h cols 16..79) -----------
    {  // stage x_t: 2048 floats, float4 per thread
      const float* xp = xseq + (size_t)(b*T_ + t)*N_*DIN_;
      const int f = tid*4;
      float4 xv = *(const float4*)&xp[f];
      const int node = f >> 4, c = f & 15;
      unsigned short s0 = f2b(xv.x), s1 = f2b(xv.y), s2 = f2b(xv.z), s3 = f2b(xv.w);
      us4 q = {s0, s1, s2, s3};
      *(us4*)&diffb[node*PD + c] = q;
      difT[(c+0)*PT + node] = s0; difT[(c+1)*PT + node] = s1;
      difT[(c+2)*PT + node] = s2; difT[(c+3)*PT + node] = s3;
    }
    dumpH(h0m, DIN_);
    __syncthreads();                                   // B1
#pragma unroll
    for (int nt = 0; nt < 5; ++nt) diffuse(nt, 80);    // dm1,dm2 of [x|h]
    __syncthreads();                                   // B2
    {
      ffrag ga[8];
      wgemm<8, 8>(ga, arow, wt + WT0G_OFF, 256, ln, lq);
      ffrag rh[4];
#pragma unroll
      for (int ct = 0; ct < 4; ++ct)
#pragma unroll
        for (int r = 0; r < 4; ++r) {
          float rr = sigm(ga[ct][r] + bgv0[ct]);
          rh[ct][r] = rr * h0m[ct][r];
          u0s[ct][r] = sigm(ga[4+ct][r] + bgv0[4+ct]);
        }
      dumpH(rh, DIN_);                                 // overwrite h-cols with r*h
    }
    __syncthreads();                                   // B3
#pragma unroll
    for (int nt = 1; nt < 5; ++nt) diffuse(nt, 80);    // dm1,dm2 of r*h cols
    __syncthreads();                                   // B4
    {
      ffrag ca[4];
      wgemm<8, 4>(ca, arow, wt + WT0C_OFF, 256, ln, lq);
#pragma unroll
      for (int ct = 0; ct < 4; ++ct)
#pragma unroll
        for (int r = 0; r < 4; ++r) {
          float cc = tanh_(ca[ct][r] + bcv0[ct]);
          float uu = u0s[ct][r];
          h0m[ct][r] = uu*h0m[ct][r] + (1.f - uu)*cc;
        }
    }
    // ---------------- Layer 1 (Cin=128: x=h0' cols 0..63, h cols 64..127) -----
    dumpH(h0m, 0);
    dumpH(h1m, 64);
    __syncthreads();                                   // B5
#pragma unroll
    for (int nt = 0; nt < 8; ++nt) diffuse(nt, 128);
    __syncthreads();                                   // B6
    {
      ffrag ga[8];
      wgemm<12, 8>(ga, arow, wt + WT1G_OFF, 384, ln, lq);
      ffrag rh[4];
#pragma unroll
      for (int ct = 0; ct < 4; ++ct)
#pragma unroll
        for (int r = 0; r < 4; ++r) {
          float rr = sigm(ga[ct][r] + bgv1[ct]);
          rh[ct][r] = rr * h1m[ct][r];
          u1s[ct][r] = sigm(ga[4+ct][r] + bgv1[4+ct]);
        }
      dumpH(rh, 64);
    }
    __syncthreads();                                   // B7
#pragma unroll
    for (int nt = 4; nt < 8; ++nt) diffuse(nt, 128);
    __syncthreads();                                   // B8
    {
      ffrag ca[4];
      wgemm<12, 4>(ca, arow, wt + WT1C_OFF, 384, ln, lq);
#pragma unroll
      for (int ct = 0; ct < 4; ++ct)
#pragma unroll
        for (int r = 0; r < 4; ++r) {
          float cc = tanh_(ca[ct][r] + bcv1[ct]);
          float uu = u1s[ct][r];
          h1m[ct][r] = uu*h1m[ct][r] + (1.f - uu)*cc;
        }
    }
  }

  // ---------------- Head: relu(h1) @ W_fc + b_fc, max over nodes --------------
  __syncthreads();
  {
    float* hb = (float*)lds;                 // [128][64] relu'd last hidden
    const int node0 = 16*w + 4*lq;
#pragma unroll
    for (int ct = 0; ct < 4; ++ct)
#pragma unroll
      for (int r = 0; r < 4; ++r) {
        float v = h1m[ct][r];
        hb[(node0 + r)*U_ + 16*ct + ln] = v > 0.f ? v : 0.f;
      }
  }
  __syncthreads();
  float* hb = (float*)lds;
  float* lb = hb + N_*U_;                    // [128][4] logits
  if (tid < N_) {
    float lg[4];
#pragma unroll
    for (int j = 0; j < 4; ++j) lg[j] = bfc[j];
    for (int ch = 0; ch < U_; ++ch) {
      float v = hb[tid*U_ + ch];
#pragma unroll
      for (int j = 0; j < 4; ++j) lg[j] += v * wfc[ch*4 + j];
    }
#pragma unroll
    for (int j = 0; j < 4; ++j) lb[tid*4 + j] = lg[j];
  }
  __syncthreads();
  if (tid < 4) {
    float m = lb[tid];
    for (int n = 1; n < N_; ++n) m = fmaxf(m, lb[n*4 + tid]);
    out[b*4 + tid] = m;
  }
}

extern "C" void kernel_launch(void* const* d_in, const int* in_sizes, int n_in,
                              void* d_out, int out_size, void* d_ws, size_t ws_size,
                              hipStream_t stream) {
  const float* xseq = (const float*)d_in[0];
  const int*   slen = (const int*)  d_in[1];
  const float* sup  = (const float*)d_in[2];
  const float* w0g  = (const float*)d_in[3];
  const float* b0g  = (const float*)d_in[4];
  const float* w0c  = (const float*)d_in[5];
  const float* b0c  = (const float*)d_in[6];
  const float* w1g  = (const float*)d_in[7];
  const float* b1g  = (const float*)d_in[8];
  const float* w1c  = (const float*)d_in[9];
  const float* b1c  = (const float*)d_in[10];
  const float* wfc  = (const float*)d_in[11];
  const float* bfc  = (const float*)d_in[12];
  float* out = (float*)d_out;
  unsigned short* wt = (unsigned short*)d_ws;

  (void)hipFuncSetAttribute((const void*)dcgru,
                            hipFuncAttributeMaxDynamicSharedMemorySize, LDS_BYTES);
  setup_wt<<<dim3((WT_TOTAL + 255)/256), dim3(256), 0, stream>>>(w0g, w0c, w1g, w1c, wt);
  setup_s2<<<dim3(64), dim3(256), 0, stream>>>(sup, wt + S2_OFF);
  dcgru<<<dim3(B_), dim3(512), LDS_BYTES, stream>>>(
      xseq, slen, sup, b0g, b0c, b1g, b1c, wfc, bfc, wt, out);
}